// Round 6
// baseline (83.502 us; speedup 1.0000x reference)
//
#include <hip/hip_runtime.h>
#include <math.h>

// Problem constants (from reference): N=256, D=128, C=1000, Q=262144
constexpr int  Nn = 256;
constexpr int  Dd = 128;
constexpr int  Cc = 1000;
constexpr int  Qq = 262144;
constexpr float PROTO_M = 0.99f;

// clang-native vector types (usable with __builtin_nontemporal_*)
typedef float vf4 __attribute__((ext_vector_type(4)));
typedef int   vi4 __attribute__((ext_vector_type(4)));

// ---- float4-unit segment sizes ----
constexpr long SEG_OUTX  = (long)Nn * Cc / 4;        // 64000   output_x copy
constexpr long SEG_QX    = (long)Nn * Dd / 4;        // 8192    q_x -> features
constexpr long SEG_QUEUE = (long)Qq * Dd / 4;        // 8388608 queue -> features + new_queue
constexpr long SEG_TGT   = (long)(2 * Nn + Qq) / 4;  // 65664   targets
constexpr long SEG_QY    = (long)Qq / 4;             // 65536   new_queue_Y / new_isID

// ---- output offsets in float units (tuple members flattened in order) ----
constexpr long OFF_OUTX = 0;
constexpr long OFF_FEAT = (long)Nn * Cc;                       // 256000
constexpr long OFF_TGT  = OFF_FEAT + (long)(2 * Nn + Qq) * Dd; // 33875968
constexpr long OFF_PROT = OFF_TGT + (2 * Nn + Qq);             // 34138624
constexpr long OFF_NQ   = OFF_PROT + (long)Cc * Dd;            // 34266624
constexpr long OFF_NQY  = OFF_NQ + (long)Qq * Dd;              // 67821056
constexpr long OFF_ISID = OFF_NQY + Qq;                        // 68083200
constexpr long OFF_PTR  = OFF_ISID + Qq;                       // 68345344

// ---- single-scheduling-wave layout ----
// 2048 blocks = 256 CU x 8 blocks/CU (32 waves/CU at 256 thr, <=64 VGPR).
// EVERY block streams one contiguous queue chunk of CH float4 units:
// 8388608 = 2048 * 4096 exactly; 4096 = 16 units/thread, no guards.
// Blocks 0..499 additionally run the proto EMA prologue (2 classes each);
// blocks 500..1011 sweep the small segments. Prologues hide under the
// other blocks' streaming; there is NO second scheduling wave (R5 lesson).
constexpr int  NBLOCKS  = 2048;
constexpr long CH       = SEG_QUEUE / NBLOCKS;                  // 4096
constexpr int  PBLOCKS  = Cc / 2;                               // 500
constexpr int  OBLOCKS  = 512;
constexpr long OTHER_TOTAL = SEG_OUTX + 2 * SEG_QX + SEG_TGT + 2 * SEG_QY + 1; // 277121

__global__ __launch_bounds__(256, 8) void mega_kernel(
    const vf4* __restrict__ q_x4, const vf4* __restrict__ k_x4,
    const vf4* __restrict__ output_x4, const vf4* __restrict__ queue4,
    const float* __restrict__ protos, const vf4* __restrict__ isID4,
    const int* __restrict__ Y, const int* __restrict__ queue_Y,
    const int* __restrict__ ptr_p, float* __restrict__ out)
{
    vf4* out4 = (vf4*)out;
    const int bid = blockIdx.x;
    const int t   = threadIdx.x;

    const int ptr_raw = *ptr_p;
    const int ptr = min(max(ptr_raw, 0), Qq - Nn);   // dynamic_update_slice clamp

    // ---------------- prologue A: prototype EMA + renormalize ----------------
    if (bid < PBLOCKS) {
        const float* q_x = (const float*)q_x4;
        const int grp = t >> 7;                      // 0 or 1: which class
        const int c   = bid * 2 + grp;
        const int d   = t & 127;
        float p = protos[(long)c * Dd + d];
        const float m = PROTO_M, om = 1.0f - PROTO_M;
        for (int i = 0; i < Nn; ++i) {
            int y = Y[i];                            // wave-uniform, L2-hot
            if (y == c) p = m * p + om * q_x[(long)i * Dd + d];
        }
        float s = p * p;                             // 128-thread sum of squares
        #pragma unroll
        for (int off = 32; off >= 1; off >>= 1) s += __shfl_xor(s, off);
        __shared__ float ws[4];
        if ((t & 63) == 0) ws[t >> 6] = s;
        __syncthreads();
        float norm = fmaxf(sqrtf(ws[2 * grp] + ws[2 * grp + 1]), 1e-12f);
        out[OFF_PROT + (long)c * Dd + d] = p / norm;
    }
    // ---------------- prologue B: small segments (3% of traffic) -------------
    else if (bid < PBLOCKS + OBLOCKS) {
        const vi4* Y4  = (const vi4*)Y;
        const vi4* qY4 = (const vi4*)queue_Y;
        const long stride = (long)OBLOCKS * 256;
        for (long v = (long)(bid - PBLOCKS) * 256 + t; v < OTHER_TOTAL; v += stride) {
            long r = v;
            if (r < SEG_OUTX) {                      // output_x passthrough
                vf4 x = __builtin_nontemporal_load(output_x4 + r);
                __builtin_nontemporal_store(x, out4 + OFF_OUTX / 4 + r);
                continue;
            }
            r -= SEG_OUTX;
            if (r < SEG_QX) {                        // features[0:N] = q_x
                vf4 x = q_x4[r];
                __builtin_nontemporal_store(x, out4 + OFF_FEAT / 4 + r);
                continue;
            }
            r -= SEG_QX;
            if (r < SEG_QX) {                        // features[N:2N] = k_x
                vf4 x = k_x4[r];
                __builtin_nontemporal_store(x, out4 + OFF_FEAT / 4 + SEG_QX + r);
                continue;
            }
            r -= SEG_QX;
            if (r < SEG_TGT) {                       // targets = concat(Y,Y,queue_Y)
                vi4 x;
                if (r < Nn / 4)          x = Y4[r];
                else if (r < 2 * Nn / 4) x = Y4[r - Nn / 4];
                else                     x = qY4[r - 2 * Nn / 4];
                vf4 o = { (float)x.x, (float)x.y, (float)x.z, (float)x.w };
                __builtin_nontemporal_store(o, out4 + OFF_TGT / 4 + r);
                continue;
            }
            r -= SEG_TGT;
            if (r < SEG_QY) {                        // new_queue_Y with splice
                vi4 x = qY4[r];
                vf4 o = { (float)x.x, (float)x.y, (float)x.z, (float)x.w };
                long e0 = r << 2;
                if (e0 + 3 >= ptr && e0 < (long)ptr + Nn) {
                    #pragma unroll
                    for (int c2 = 0; c2 < 4; ++c2) {
                        long e = e0 + c2;
                        if (e >= ptr && e < (long)ptr + Nn) o[c2] = (float)Y[e - ptr];
                    }
                }
                __builtin_nontemporal_store(o, out4 + OFF_NQY / 4 + r);
                continue;
            }
            r -= SEG_QY;
            if (r < SEG_QY) {                        // new_isID with splice
                vf4 o = __builtin_nontemporal_load(isID4 + r);
                long e0 = r << 2;
                if (e0 + 3 >= ptr && e0 < (long)ptr + Nn) {
                    #pragma unroll
                    for (int c2 = 0; c2 < 4; ++c2) {
                        long e = e0 + c2;
                        if (e >= ptr && e < (long)ptr + Nn) o[c2] = 1.0f;
                    }
                }
                __builtin_nontemporal_store(o, out4 + OFF_ISID / 4 + r);
                continue;
            }
            out[OFF_PTR] = (float)((ptr_raw + Nn) % Qq);   // new_ptr
        }
    }

    // ---------------- main: queue chunk (every block, 97.6% of traffic) ------
    {
        vf4* __restrict__ feat4 = out4 + OFF_FEAT / 4 + 2 * SEG_QX;
        vf4* __restrict__ nq4   = out4 + OFF_NQ / 4;
        const long s = (long)bid * CH;
        #pragma unroll
        for (int it = 0; it < 4; ++it) {
            const long base = s + (long)it * 1024 + t;
            // 4 independent loads in flight per thread
            vf4 a0 = __builtin_nontemporal_load(queue4 + base);
            vf4 a1 = __builtin_nontemporal_load(queue4 + base + 256);
            vf4 a2 = __builtin_nontemporal_load(queue4 + base + 512);
            vf4 a3 = __builtin_nontemporal_load(queue4 + base + 768);
            __builtin_nontemporal_store(a0, feat4 + base);
            __builtin_nontemporal_store(a1, feat4 + base + 256);
            __builtin_nontemporal_store(a2, feat4 + base + 512);
            __builtin_nontemporal_store(a3, feat4 + base + 768);
            vf4 n0 = a0, n1 = a1, n2 = a2, n3 = a3;
            const int r0 = (int)(base >> 5);         // D/4 = 32 units per row
            const int r1 = (int)((base + 256) >> 5);
            const int r2 = (int)((base + 512) >> 5);
            const int r3 = (int)((base + 768) >> 5);
            if (r0 >= ptr && r0 < ptr + Nn) n0 = k_x4[((long)(r0 - ptr) << 5) + (base & 31)];
            if (r1 >= ptr && r1 < ptr + Nn) n1 = k_x4[((long)(r1 - ptr) << 5) + ((base + 256) & 31)];
            if (r2 >= ptr && r2 < ptr + Nn) n2 = k_x4[((long)(r2 - ptr) << 5) + ((base + 512) & 31)];
            if (r3 >= ptr && r3 < ptr + Nn) n3 = k_x4[((long)(r3 - ptr) << 5) + ((base + 768) & 31)];
            __builtin_nontemporal_store(n0, nq4 + base);
            __builtin_nontemporal_store(n1, nq4 + base + 256);
            __builtin_nontemporal_store(n2, nq4 + base + 512);
            __builtin_nontemporal_store(n3, nq4 + base + 768);
        }
    }
}

extern "C" void kernel_launch(void* const* d_in, const int* in_sizes, int n_in,
                              void* d_out, int out_size, void* d_ws, size_t ws_size,
                              hipStream_t stream)
{
    const float* q_x      = (const float*)d_in[0];
    const float* k_x      = (const float*)d_in[1];
    const float* output_x = (const float*)d_in[2];
    const float* queue    = (const float*)d_in[3];
    const float* protos   = (const float*)d_in[4];
    const float* isID     = (const float*)d_in[5];
    const int*   Y        = (const int*)d_in[6];
    const int*   queue_Y  = (const int*)d_in[7];
    const int*   ptr_p    = (const int*)d_in[8];
    float* out = (float*)d_out;

    hipLaunchKernelGGL(mega_kernel, dim3(NBLOCKS), dim3(256), 0, stream,
                       (const vf4*)q_x, (const vf4*)k_x,
                       (const vf4*)output_x, (const vf4*)queue,
                       protos, (const vf4*)isID, Y, queue_Y, ptr_p, out);
}

// Round 7
// 67.664 us; speedup vs baseline: 1.2341x; 1.2341x over previous
//
#include <hip/hip_runtime.h>
#include <math.h>

// Problem constants (from reference): N=256, D=128, C=1000, Q=262144
constexpr int  Nn = 256;
constexpr int  Dd = 128;
constexpr int  Cc = 1000;
constexpr int  Qq = 262144;
constexpr float PROTO_M = 0.99f;

// clang-native vector types (usable with __builtin_nontemporal_*)
typedef float vf4 __attribute__((ext_vector_type(4)));
typedef int   vi4 __attribute__((ext_vector_type(4)));

// ---- float4-unit segment sizes ----
constexpr long SEG_OUTX  = (long)Nn * Cc / 4;        // 64000   output_x copy
constexpr long SEG_QX    = (long)Nn * Dd / 4;        // 8192    q_x -> features
constexpr long SEG_QUEUE = (long)Qq * Dd / 4;        // 8388608 queue -> features + new_queue
constexpr long SEG_TGT   = (long)(2 * Nn + Qq) / 4;  // 65664   targets
constexpr long SEG_QY    = (long)Qq / 4;             // 65536   new_queue_Y / new_isID

// ---- output offsets in float units (tuple members flattened in order) ----
constexpr long OFF_OUTX = 0;
constexpr long OFF_FEAT = (long)Nn * Cc;                       // 256000
constexpr long OFF_TGT  = OFF_FEAT + (long)(2 * Nn + Qq) * Dd; // 33875968
constexpr long OFF_PROT = OFF_TGT + (2 * Nn + Qq);             // 34138624
constexpr long OFF_NQ   = OFF_PROT + (long)Cc * Dd;            // 34266624
constexpr long OFF_NQY  = OFF_NQ + (long)Qq * Dd;              // 67821056
constexpr long OFF_ISID = OFF_NQY + Qq;                        // 68083200
constexpr long OFF_PTR  = OFF_ISID + Qq;                       // 68345344

// ---- single-scheduling-wave layout (kept from R6) ----
// 2048 blocks = 256 CU x 8 blocks/CU. Every block streams one contiguous
// queue chunk of 4096 float4 units (8388608 = 2048*4096, no guards).
// Blocks 0..499 run the proto-EMA prologue; 500..1011 the small segments.
// R7 single-variable change vs R6: STORES ARE PLAIN (write-back, allocate)
// instead of nontemporal. Calibration: fillBuffer (plain) = 7.0 TB/s,
// copy ubench (plain) = 6.3 TB/s; all nt-store variants plateau at 4.9.
constexpr int  NBLOCKS  = 2048;
constexpr long CH       = SEG_QUEUE / NBLOCKS;                  // 4096
constexpr int  PBLOCKS  = Cc / 2;                               // 500
constexpr int  OBLOCKS  = 512;
constexpr long OTHER_TOTAL = SEG_OUTX + 2 * SEG_QX + SEG_TGT + 2 * SEG_QY + 1; // 277121

__global__ __launch_bounds__(256, 8) void mega_kernel(
    const vf4* __restrict__ q_x4, const vf4* __restrict__ k_x4,
    const vf4* __restrict__ output_x4, const vf4* __restrict__ queue4,
    const float* __restrict__ protos, const vf4* __restrict__ isID4,
    const int* __restrict__ Y, const int* __restrict__ queue_Y,
    const int* __restrict__ ptr_p, float* __restrict__ out)
{
    vf4* out4 = (vf4*)out;
    const int bid = blockIdx.x;
    const int t   = threadIdx.x;

    const int ptr_raw = *ptr_p;
    const int ptr = min(max(ptr_raw, 0), Qq - Nn);   // dynamic_update_slice clamp

    // ---------------- prologue A: prototype EMA + renormalize ----------------
    if (bid < PBLOCKS) {
        const float* q_x = (const float*)q_x4;
        const int grp = t >> 7;                      // 0 or 1: which class
        const int c   = bid * 2 + grp;
        const int d   = t & 127;
        float p = protos[(long)c * Dd + d];
        const float m = PROTO_M, om = 1.0f - PROTO_M;
        for (int i = 0; i < Nn; ++i) {
            int y = Y[i];                            // wave-uniform, L2-hot
            if (y == c) p = m * p + om * q_x[(long)i * Dd + d];
        }
        float s = p * p;                             // 128-thread sum of squares
        #pragma unroll
        for (int off = 32; off >= 1; off >>= 1) s += __shfl_xor(s, off);
        __shared__ float ws[4];
        if ((t & 63) == 0) ws[t >> 6] = s;
        __syncthreads();
        float norm = fmaxf(sqrtf(ws[2 * grp] + ws[2 * grp + 1]), 1e-12f);
        out[OFF_PROT + (long)c * Dd + d] = p / norm;
    }
    // ---------------- prologue B: small segments (3% of traffic) -------------
    else if (bid < PBLOCKS + OBLOCKS) {
        const vi4* Y4  = (const vi4*)Y;
        const vi4* qY4 = (const vi4*)queue_Y;
        const long stride = (long)OBLOCKS * 256;
        for (long v = (long)(bid - PBLOCKS) * 256 + t; v < OTHER_TOTAL; v += stride) {
            long r = v;
            if (r < SEG_OUTX) {                      // output_x passthrough
                vf4 x = __builtin_nontemporal_load(output_x4 + r);
                out4[OFF_OUTX / 4 + r] = x;
                continue;
            }
            r -= SEG_OUTX;
            if (r < SEG_QX) {                        // features[0:N] = q_x
                out4[OFF_FEAT / 4 + r] = q_x4[r];
                continue;
            }
            r -= SEG_QX;
            if (r < SEG_QX) {                        // features[N:2N] = k_x
                out4[OFF_FEAT / 4 + SEG_QX + r] = k_x4[r];
                continue;
            }
            r -= SEG_QX;
            if (r < SEG_TGT) {                       // targets = concat(Y,Y,queue_Y)
                vi4 x;
                if (r < Nn / 4)          x = Y4[r];
                else if (r < 2 * Nn / 4) x = Y4[r - Nn / 4];
                else                     x = qY4[r - 2 * Nn / 4];
                vf4 o = { (float)x.x, (float)x.y, (float)x.z, (float)x.w };
                out4[OFF_TGT / 4 + r] = o;
                continue;
            }
            r -= SEG_TGT;
            if (r < SEG_QY) {                        // new_queue_Y with splice
                vi4 x = qY4[r];
                vf4 o = { (float)x.x, (float)x.y, (float)x.z, (float)x.w };
                long e0 = r << 2;
                if (e0 + 3 >= ptr && e0 < (long)ptr + Nn) {
                    #pragma unroll
                    for (int c2 = 0; c2 < 4; ++c2) {
                        long e = e0 + c2;
                        if (e >= ptr && e < (long)ptr + Nn) o[c2] = (float)Y[e - ptr];
                    }
                }
                out4[OFF_NQY / 4 + r] = o;
                continue;
            }
            r -= SEG_QY;
            if (r < SEG_QY) {                        // new_isID with splice
                vf4 o = __builtin_nontemporal_load(isID4 + r);
                long e0 = r << 2;
                if (e0 + 3 >= ptr && e0 < (long)ptr + Nn) {
                    #pragma unroll
                    for (int c2 = 0; c2 < 4; ++c2) {
                        long e = e0 + c2;
                        if (e >= ptr && e < (long)ptr + Nn) o[c2] = 1.0f;
                    }
                }
                out4[OFF_ISID / 4 + r] = o;
                continue;
            }
            out[OFF_PTR] = (float)((ptr_raw + Nn) % Qq);   // new_ptr
        }
    }

    // ---------------- main: queue chunk (every block, 97.6% of traffic) ------
    {
        vf4* __restrict__ feat4 = out4 + OFF_FEAT / 4 + 2 * SEG_QX;
        vf4* __restrict__ nq4   = out4 + OFF_NQ / 4;
        const long s = (long)bid * CH;
        #pragma unroll
        for (int it = 0; it < 4; ++it) {
            const long base = s + (long)it * 1024 + t;
            // 4 independent loads in flight per thread
            vf4 a0 = __builtin_nontemporal_load(queue4 + base);
            vf4 a1 = __builtin_nontemporal_load(queue4 + base + 256);
            vf4 a2 = __builtin_nontemporal_load(queue4 + base + 512);
            vf4 a3 = __builtin_nontemporal_load(queue4 + base + 768);
            feat4[base]       = a0;
            feat4[base + 256] = a1;
            feat4[base + 512] = a2;
            feat4[base + 768] = a3;
            vf4 n0 = a0, n1 = a1, n2 = a2, n3 = a3;
            const int r0 = (int)(base >> 5);         // D/4 = 32 units per row
            const int r1 = (int)((base + 256) >> 5);
            const int r2 = (int)((base + 512) >> 5);
            const int r3 = (int)((base + 768) >> 5);
            if (r0 >= ptr && r0 < ptr + Nn) n0 = k_x4[((long)(r0 - ptr) << 5) + (base & 31)];
            if (r1 >= ptr && r1 < ptr + Nn) n1 = k_x4[((long)(r1 - ptr) << 5) + ((base + 256) & 31)];
            if (r2 >= ptr && r2 < ptr + Nn) n2 = k_x4[((long)(r2 - ptr) << 5) + ((base + 512) & 31)];
            if (r3 >= ptr && r3 < ptr + Nn) n3 = k_x4[((long)(r3 - ptr) << 5) + ((base + 768) & 31)];
            nq4[base]       = n0;
            nq4[base + 256] = n1;
            nq4[base + 512] = n2;
            nq4[base + 768] = n3;
        }
    }
}

extern "C" void kernel_launch(void* const* d_in, const int* in_sizes, int n_in,
                              void* d_out, int out_size, void* d_ws, size_t ws_size,
                              hipStream_t stream)
{
    const float* q_x      = (const float*)d_in[0];
    const float* k_x      = (const float*)d_in[1];
    const float* output_x = (const float*)d_in[2];
    const float* queue    = (const float*)d_in[3];
    const float* protos   = (const float*)d_in[4];
    const float* isID     = (const float*)d_in[5];
    const int*   Y        = (const int*)d_in[6];
    const int*   queue_Y  = (const int*)d_in[7];
    const int*   ptr_p    = (const int*)d_in[8];
    float* out = (float*)d_out;

    hipLaunchKernelGGL(mega_kernel, dim3(NBLOCKS), dim3(256), 0, stream,
                       (const vf4*)q_x, (const vf4*)k_x,
                       (const vf4*)output_x, (const vf4*)queue,
                       protos, (const vf4*)isID, Y, queue_Y, ptr_p, out);
}